// Round 9
// baseline (7575.541 us; speedup 1.0000x reference)
//
#include <hip/hip_runtime.h>

// Seq2SeqLSTMForecaster on MI355X — round 9.
// Discovery (R8 counters): VGPR_Count==128 while w[4][32] alone is 128 floats
// -> the compiler was RE-LOADING weights from L2 inside the step loop in all
// recurrent kernels. Fix: quad-gate with 8-way k-split at 1024 thr: w[4][16]
// = 64 VGPR, genuinely resident under the 128-cap, 16 waves/CU.
//  - kA : enc L0, 1024 thr, 8-way-k quad-gate; emits ys0T k-major.
//  - kX : x-proj GEMM upgraded: 128x128 tile, 8x8 micro (64 FMA per 4 LDS
//         reads), B read as two stride-4 float4 (n, n+64) -> 2-way = free
//         (old stride-8 read was 4-way conflicted); 2 blocks/CU.
//  - kB2: enc L1, 1024 thr, 8-way-k quad-gate, X1 prefetch (act threads).
//  - kD : decoder, 1024 thr, 8-way-k quad-gate both dots; 16 waves hide the
//         phase-3 L2 weight stream; head/act on lower 512 threads.

#define B_    1024
#define T_    672
#define H_    128
#define G_    512      // 4*H
#define TGT_  96
#define NBLK_ 256

__device__ __forceinline__ float sigm(float x)   { return 1.f / (1.f + __expf(-x)); }
__device__ __forceinline__ float tanh_f(float x) { return 1.f - 2.f / (1.f + __expf(2.f * x)); }

// ---------------------------------------------------------------- prep ------
struct PrepArgs {
    const float* t_src[4];   // eWhh0, eWih1, eWhh1, dWhh0 -> [128,512]
    float*       t_dst[4];
    const float* d1x;  const float* d1h;  float* pack;   // dec L1 8-wide pack
};

__global__ void kPrep(PrepArgs a) {
    const int m = blockIdx.x;
    if (m < 4) {
        for (int i = threadIdx.x; i < G_ * H_; i += blockDim.x) {
            const int j = i >> 7, k = i & 127;
            a.t_dst[m][k * G_ + j] = a.t_src[m][i];
        }
    } else {
        // pack[(k*128 + j4)*8 + g]   = dWih1[j4+128g][k]
        // pack[(k*128 + j4)*8 + 4+g] = dWhh1[j4+128g][k]
        for (int i = threadIdx.x; i < H_ * H_; i += blockDim.x) {
            const int k = i >> 7, j4 = i & 127;
            float* p = a.pack + ((size_t)k * H_ + j4) * 8;
#pragma unroll
            for (int g = 0; g < 4; g++) {
                p[g]     = a.d1x[(j4 + 128 * g) * H_ + k];
                p[4 + g] = a.d1h[(j4 + 128 * g) * H_ + k];
            }
        }
    }
}

// --------------------------- enc L0 (1024 thr, 8-way k, quad-gate) ----------
__global__ __launch_bounds__(1024, 4) void kA(
    const float* __restrict__ feat,   // [B,T]
    const float* __restrict__ whhT,   // [128,512] enc_Whh0^T
    const float* __restrict__ wih0,   // [512]
    const float* __restrict__ bias,   // [512]
    float* __restrict__ ys0T,         // [CL][128][1024] k-major
    float* __restrict__ hS, float* __restrict__ cS,
    int t0, int CL)
{
    __shared__ __align__(16) float h_sh[H_ * 4];     // [hid][bb]
    __shared__ __align__(16) float zp[8 * 2048];     // [ko][batch][gate] 64KB
    __shared__ __align__(16) float f_sh[84 * 4];

    const int tid = threadIdx.x;
    const int hid = tid & 127;        // gate group (dot) / act hid
    const int ko  = tid >> 7;         // k-octant 0..7
    const int B0  = blockIdx.x * 4;

    float w[4][16];
#pragma unroll
    for (int g = 0; g < 4; g++)
#pragma unroll
        for (int k = 0; k < 16; k++)
            w[g][k] = whhT[(ko * 16 + k) * G_ + hid + 128 * g];

    const float bi = bias[hid],          bf = bias[hid + 128];
    const float bg = bias[hid + 256],    bo = bias[hid + 384];
    const float wxi = wih0[hid],         wxf = wih0[hid + 128];
    const float wxg = wih0[hid + 256],   wxo = wih0[hid + 384];

    for (int i = tid; i < CL * 4; i += 1024)
        f_sh[i] = feat[(B0 + (i & 3)) * T_ + t0 + (i >> 2)];

    const int bb = ko & 3;            // act batch (only meaningful for tid<512)
    float c = 0.f;
    if (tid < 512) {
        float hv = 0.f;
        if (t0 != 0) { c = cS[(B0 + bb) * H_ + hid]; hv = hS[(B0 + bb) * H_ + hid]; }
        h_sh[hid * 4 + bb] = hv;
    }
    __syncthreads();

    const float* hb = h_sh + ko * 64;     // k-range ko*16..+15, layout [k][batch]
    for (int dt = 0; dt < CL; dt++) {
        if (tid < 512 && dt > 0)
            ys0T[((size_t)(dt - 1) * H_ + (tid >> 2)) * B_ + B0 + (tid & 3)] = h_sh[tid];

        float a[4][4] = {};
#pragma unroll
        for (int k = 0; k < 16; k++) {
            const float4 h4 = *(const float4*)&hb[k * 4];   // uniform broadcast
#pragma unroll
            for (int g = 0; g < 4; g++) {
                a[g][0] = __fmaf_rn(h4.x, w[g][k], a[g][0]);
                a[g][1] = __fmaf_rn(h4.y, w[g][k], a[g][1]);
                a[g][2] = __fmaf_rn(h4.z, w[g][k], a[g][2]);
                a[g][3] = __fmaf_rn(h4.w, w[g][k], a[g][3]);
            }
        }
#pragma unroll
        for (int g = 0; g < 4; g++)
#pragma unroll
            for (int b = 0; b < 4; b++)
                zp[ko * 2048 + b * 512 + hid + 128 * g] = a[g][b];
        __syncthreads();

        if (tid < 512) {
            const float x = f_sh[dt * 4 + bb];
            const int base = bb * 512 + hid;
            float zi = __fmaf_rn(wxi, x, bi);
            float zf = __fmaf_rn(wxf, x, bf);
            float zg = __fmaf_rn(wxg, x, bg);
            float zo = __fmaf_rn(wxo, x, bo);
#pragma unroll
            for (int q = 0; q < 8; q++) {
                zi += zp[q * 2048 + base];
                zf += zp[q * 2048 + base + 128];
                zg += zp[q * 2048 + base + 256];
                zo += zp[q * 2048 + base + 384];
            }
            c = sigm(zf) * c + sigm(zi) * tanh_f(zg);
            h_sh[hid * 4 + bb] = sigm(zo) * tanh_f(c);
        }
        __syncthreads();
    }
    if (tid < 512) {
        ys0T[((size_t)(CL - 1) * H_ + (tid >> 2)) * B_ + B0 + (tid & 3)] = h_sh[tid];
        hS[(B0 + bb) * H_ + hid] = h_sh[hid * 4 + bb];
        cS[(B0 + bb) * H_ + hid] = c;
    }
}

// ----------------------- X1 GEMM: 128x128 tile, 8x8 micro, split-B ----------
__global__ __launch_bounds__(256, 2) void kX(
    const float* __restrict__ ys0T,   // [CL][128][1024]
    const float* __restrict__ wT,     // [128][512]
    const float* __restrict__ bias,   // [512]
    float* __restrict__ X1)           // [CL][1024][512]
{
    __shared__ __align__(16) float As[64][132];   // [k][m] 33.8KB
    __shared__ __align__(16) float Bs[64][132];   // [k][n] 33.8KB

    const int tid = threadIdx.x;
    const int m0 = blockIdx.x * 128;
    const int n0 = blockIdx.y * 128;
    const int dt = blockIdx.z;
    const float* A = ys0T + (size_t)dt * H_ * B_;

    const int tx = tid & 15, ty = tid >> 4;
    float acc[8][8] = {};

#pragma unroll
    for (int ks = 0; ks < 2; ks++) {
        if (ks) __syncthreads();
        for (int t = tid; t < 64 * 32; t += 256) {
            const int r = t >> 5, q = t & 31;
            *(float4*)&As[r][q * 4] = *(const float4*)&A[(size_t)(ks * 64 + r) * B_ + m0 + q * 4];
        }
        for (int t = tid; t < 64 * 32; t += 256) {
            const int r = t >> 5, q = t & 31;
            *(float4*)&Bs[r][q * 4] = *(const float4*)&wT[(size_t)(ks * 64 + r) * G_ + n0 + q * 4];
        }
        __syncthreads();

#pragma unroll 4
        for (int k = 0; k < 64; k++) {
            float av[8], bv[8];
            *(float4*)&av[0] = *(const float4*)&As[k][ty * 8];       // broadcast x16
            *(float4*)&av[4] = *(const float4*)&As[k][ty * 8 + 4];
            *(float4*)&bv[0] = *(const float4*)&Bs[k][tx * 4];       // stride-4: 2-way free
            *(float4*)&bv[4] = *(const float4*)&Bs[k][64 + tx * 4];
#pragma unroll
            for (int i = 0; i < 8; i++)
#pragma unroll
                for (int j = 0; j < 8; j++)
                    acc[i][j] = __fmaf_rn(av[i], bv[j], acc[i][j]);
        }
    }

    float4 bv0 = *(const float4*)&bias[n0 + tx * 4];
    float4 bv1 = *(const float4*)&bias[n0 + 64 + tx * 4];
#pragma unroll
    for (int i = 0; i < 8; i++) {
        float4 o0, o1;
        o0.x = acc[i][0] + bv0.x; o0.y = acc[i][1] + bv0.y;
        o0.z = acc[i][2] + bv0.z; o0.w = acc[i][3] + bv0.w;
        o1.x = acc[i][4] + bv1.x; o1.y = acc[i][5] + bv1.y;
        o1.z = acc[i][6] + bv1.z; o1.w = acc[i][7] + bv1.w;
        float* orow = &X1[((size_t)dt * B_ + m0 + ty * 8 + i) * G_ + n0];
        *(float4*)&orow[tx * 4]      = o0;
        *(float4*)&orow[64 + tx * 4] = o1;
    }
}

// --------------------------- enc L1 (1024 thr, 8-way k, quad-gate) ----------
__global__ __launch_bounds__(1024, 4) void kB2(
    const float* __restrict__ X1,     // [CL][B][512] x-projection (+bias)
    const float* __restrict__ whhT,   // [128,512] enc_Whh1^T
    float* __restrict__ hS, float* __restrict__ cS,
    int t0, int CL)
{
    __shared__ __align__(16) float h_sh[H_ * 4];
    __shared__ __align__(16) float zp[8 * 2048];

    const int tid = threadIdx.x;
    const int hid = tid & 127;
    const int ko  = tid >> 7;
    const int B0  = blockIdx.x * 4;

    float w[4][16];
#pragma unroll
    for (int g = 0; g < 4; g++)
#pragma unroll
        for (int k = 0; k < 16; k++)
            w[g][k] = whhT[(ko * 16 + k) * G_ + hid + 128 * g];

    const int bb = ko & 3;
    float c = 0.f;
    if (tid < 512) {
        float hv = 0.f;
        if (t0 != 0) { c = cS[(B0 + bb) * H_ + hid]; hv = hS[(B0 + bb) * H_ + hid]; }
        h_sh[hid * 4 + bb] = hv;
    }
    __syncthreads();

    const float* hb = h_sh + ko * 64;
    for (int dt = 0; dt < CL; dt++) {
        float xg0 = 0.f, xg1 = 0.f, xg2 = 0.f, xg3 = 0.f;
        if (tid < 512) {
            const size_t xb = ((size_t)dt * B_ + B0 + bb) * G_ + hid;
            xg0 = X1[xb]; xg1 = X1[xb + 128]; xg2 = X1[xb + 256]; xg3 = X1[xb + 384];
        }
        float a[4][4] = {};
#pragma unroll
        for (int k = 0; k < 16; k++) {
            const float4 h4 = *(const float4*)&hb[k * 4];
#pragma unroll
            for (int g = 0; g < 4; g++) {
                a[g][0] = __fmaf_rn(h4.x, w[g][k], a[g][0]);
                a[g][1] = __fmaf_rn(h4.y, w[g][k], a[g][1]);
                a[g][2] = __fmaf_rn(h4.z, w[g][k], a[g][2]);
                a[g][3] = __fmaf_rn(h4.w, w[g][k], a[g][3]);
            }
        }
#pragma unroll
        for (int g = 0; g < 4; g++)
#pragma unroll
            for (int b = 0; b < 4; b++)
                zp[ko * 2048 + b * 512 + hid + 128 * g] = a[g][b];
        __syncthreads();

        if (tid < 512) {
            const int base = bb * 512 + hid;
            float zi = xg0, zf = xg1, zg = xg2, zo = xg3;
#pragma unroll
            for (int q = 0; q < 8; q++) {
                zi += zp[q * 2048 + base];
                zf += zp[q * 2048 + base + 128];
                zg += zp[q * 2048 + base + 256];
                zo += zp[q * 2048 + base + 384];
            }
            c = sigm(zf) * c + sigm(zi) * tanh_f(zg);
            h_sh[hid * 4 + bb] = sigm(zo) * tanh_f(c);
        }
        __syncthreads();
    }
    if (tid < 512) {
        hS[(B0 + bb) * H_ + hid] = h_sh[hid * 4 + bb];
        cS[(B0 + bb) * H_ + hid] = c;
    }
}

// --------------------------- decoder (1024 thr, 8-way k, quad-gate) ---------
__global__ __launch_bounds__(1024, 4) void kD(
    const float* __restrict__ h1S, const float* __restrict__ c1S,
    const float* __restrict__ h2S, const float* __restrict__ c2S,
    const float* __restrict__ whh0T,  // [128][512] dec_Whh0^T (resident 64 reg)
    const float* __restrict__ wih0,   // [512]
    const float* __restrict__ b0,
    const float* __restrict__ packD1, // [128][128][8]
    const float* __restrict__ b1,
    const float* __restrict__ wo1,    // [128][128] W_out1 [hid][k] -> LDS rows
    const float* __restrict__ bo1,
    const float* __restrict__ wo2,
    const float* __restrict__ bo2,
    float* __restrict__ out)          // [B,TGT]
{
    __shared__ __align__(16) float h1_sh[H_ * 4];
    __shared__ __align__(16) float h2_sh[H_ * 4];
    __shared__ __align__(16) float h2t[4][H_];       // [bb][hid]
    __shared__ __align__(16) float zp[8 * 2048];     // 64KB
    __shared__ __align__(16) float wo1s[H_ * 132];   // 67.6KB
    __shared__ float rp[8];

    const int tid = threadIdx.x;
    const int hid = tid & 127;
    const int ko  = tid >> 7;
    const int B0  = blockIdx.x * 4;
    const int bb  = ko & 3;

    float w0[4][16];
#pragma unroll
    for (int g = 0; g < 4; g++)
#pragma unroll
        for (int k = 0; k < 16; k++)
            w0[g][k] = whh0T[(ko * 16 + k) * G_ + hid + 128 * g];

    const float b0i = b0[hid],         b0f = b0[hid + 128];
    const float b0g = b0[hid + 256],   b0o = b0[hid + 384];
    const float wxi = wih0[hid],       wxf = wih0[hid + 128];
    const float wxg = wih0[hid + 256], wxo = wih0[hid + 384];
    const float b1i = b1[hid],         b1f = b1[hid + 128];
    const float b1g = b1[hid + 256],   b1o = b1[hid + 384];

    for (int t = tid; t < H_ * 32; t += 1024) {
        const int r = t >> 5, q = t & 31;
        *(float4*)&wo1s[r * 132 + q * 4] = *(const float4*)&wo1[r * H_ + q * 4];
    }

    const float wo2v = wo2[hid];
    const float bo1j = bo1[hid];
    const float bo2v = bo2[0];

    float c1 = 0.f, c2 = 0.f;
    if (tid < 512) {
        c1 = c1S[(B0 + bb) * H_ + hid];
        c2 = c2S[(B0 + bb) * H_ + hid];
        h1_sh[hid * 4 + bb] = h1S[(B0 + bb) * H_ + hid];
        const float h2v = h2S[(B0 + bb) * H_ + hid];
        h2_sh[hid * 4 + bb] = h2v;
        h2t[bb][hid] = h2v;
    }
    if (tid < 8) rp[tid] = -0.5f * bo2v;   // so pred(step 0) = 0
    __syncthreads();

    const float* hb1 = h1_sh + ko * 64;
    const float* hb2 = h2_sh + ko * 64;
    const float* pk  = packD1 + ((size_t)ko * 16 * H_ + hid) * 8;

    for (int s = 0; s < TGT_; s++) {
        // ===== phase 1: L0 h-dot (all waves) + head of h2(s-1) (lower half) ==
        {
            float a[4][4] = {};
#pragma unroll
            for (int k = 0; k < 16; k++) {
                const float4 h4 = *(const float4*)&hb1[k * 4];
#pragma unroll
                for (int g = 0; g < 4; g++) {
                    a[g][0] = __fmaf_rn(h4.x, w0[g][k], a[g][0]);
                    a[g][1] = __fmaf_rn(h4.y, w0[g][k], a[g][1]);
                    a[g][2] = __fmaf_rn(h4.z, w0[g][k], a[g][2]);
                    a[g][3] = __fmaf_rn(h4.w, w0[g][k], a[g][3]);
                }
            }
#pragma unroll
            for (int g = 0; g < 4; g++)
#pragma unroll
                for (int b = 0; b < 4; b++)
                    zp[ko * 2048 + b * 512 + hid + 128 * g] = a[g][b];
        }
        if (tid < 512) {
            float hacc = bo1j;
#pragma unroll
            for (int q = 0; q < 32; q++) {
                const float4 hq = *(const float4*)&h2t[bb][q * 4];
                const float4 wq = *(const float4*)&wo1s[hid * 132 + q * 4];
                hacc = __fmaf_rn(hq.x, wq.x, hacc);
                hacc = __fmaf_rn(hq.y, wq.y, hacc);
                hacc = __fmaf_rn(hq.z, wq.z, hacc);
                hacc = __fmaf_rn(hq.w, wq.w, hacc);
            }
            float p = fmaxf(hacc, 0.f) * wo2v;
            p += __shfl_down(p, 32); p += __shfl_down(p, 16); p += __shfl_down(p, 8);
            p += __shfl_down(p, 4);  p += __shfl_down(p, 2);  p += __shfl_down(p, 1);
            if ((tid & 63) == 0) rp[tid >> 6] = p;
        }
        __syncthreads();

        // ===== phase 2: L0 act (+ x-term via pred), out write ================
        if (tid < 512) {
            const float pred = rp[2 * bb] + rp[2 * bb + 1] + bo2v;
            if (hid == 0 && s > 0) out[(B0 + bb) * TGT_ + (s - 1)] = pred;
            const int base = bb * 512 + hid;
            float zi = __fmaf_rn(wxi, pred, b0i);
            float zf = __fmaf_rn(wxf, pred, b0f);
            float zg = __fmaf_rn(wxg, pred, b0g);
            float zo = __fmaf_rn(wxo, pred, b0o);
#pragma unroll
            for (int q = 0; q < 8; q++) {
                zi += zp[q * 2048 + base];
                zf += zp[q * 2048 + base + 128];
                zg += zp[q * 2048 + base + 256];
                zo += zp[q * 2048 + base + 384];
            }
            c1 = sigm(zf) * c1 + sigm(zi) * tanh_f(zg);
            h1_sh[hid * 4 + bb] = sigm(zo) * tanh_f(c1);
        }
        __syncthreads();

        // ===== phase 3: L1 dot (L2 stream, 32B per thread per k, 16 waves) ===
        {
            float d[4][4] = {};
#pragma unroll
            for (int k = 0; k < 16; k++) {
                const float4 wi = *(const float4*)&pk[(size_t)k * 1024];
                const float4 wh = *(const float4*)&pk[(size_t)k * 1024 + 4];
                const float4 p1 = *(const float4*)&hb1[k * 4];
                const float4 p2 = *(const float4*)&hb2[k * 4];
                d[0][0] = __fmaf_rn(p1.x, wi.x, __fmaf_rn(p2.x, wh.x, d[0][0]));
                d[0][1] = __fmaf_rn(p1.y, wi.x, __fmaf_rn(p2.y, wh.x, d[0][1]));
                d[0][2] = __fmaf_rn(p1.z, wi.x, __fmaf_rn(p2.z, wh.x, d[0][2]));
                d[0][3] = __fmaf_rn(p1.w, wi.x, __fmaf_rn(p2.w, wh.x, d[0][3]));
                d[1][0] = __fmaf_rn(p1.x, wi.y, __fmaf_rn(p2.x, wh.y, d[1][0]));
                d[1][1] = __fmaf_rn(p1.y, wi.y, __fmaf_rn(p2.y, wh.y, d[1][1]));
                d[1][2] = __fmaf_rn(p1.z, wi.y, __fmaf_rn(p2.z, wh.y, d[1][2]));
                d[1][3] = __fmaf_rn(p1.w, wi.y, __fmaf_rn(p2.w, wh.y, d[1][3]));
                d[2][0] = __fmaf_rn(p1.x, wi.z, __fmaf_rn(p2.x, wh.z, d[2][0]));
                d[2][1] = __fmaf_rn(p1.y, wi.z, __fmaf_rn(p2.y, wh.z, d[2][1]));
                d[2][2] = __fmaf_rn(p1.z, wi.z, __fmaf_rn(p2.z, wh.z, d[2][2]));
                d[2][3] = __fmaf_rn(p1.w, wi.z, __fmaf_rn(p2.w, wh.z, d[2][3]));
                d[3][0] = __fmaf_rn(p1.x, wi.w, __fmaf_rn(p2.x, wh.w, d[3][0]));
                d[3][1] = __fmaf_rn(p1.y, wi.w, __fmaf_rn(p2.y, wh.w, d[3][1]));
                d[3][2] = __fmaf_rn(p1.z, wi.w, __fmaf_rn(p2.z, wh.w, d[3][2]));
                d[3][3] = __fmaf_rn(p1.w, wi.w, __fmaf_rn(p2.w, wh.w, d[3][3]));
            }
#pragma unroll
            for (int g = 0; g < 4; g++)
#pragma unroll
                for (int b = 0; b < 4; b++)
                    zp[ko * 2048 + b * 512 + hid + 128 * g] = d[g][b];
        }
        __syncthreads();

        // ===== phase 4: L1 act ==============================================
        if (tid < 512) {
            const int base = bb * 512 + hid;
            float zi = b1i, zf = b1f, zg = b1g, zo = b1o;
#pragma unroll
            for (int q = 0; q < 8; q++) {
                zi += zp[q * 2048 + base];
                zf += zp[q * 2048 + base + 128];
                zg += zp[q * 2048 + base + 256];
                zo += zp[q * 2048 + base + 384];
            }
            c2 = sigm(zf) * c2 + sigm(zi) * tanh_f(zg);
            const float h2v = sigm(zo) * tanh_f(c2);
            h2_sh[hid * 4 + bb] = h2v;
            h2t[bb][hid] = h2v;
        }
        __syncthreads();
    }

    // ===== epilogue: head of final h2 -> out[..][95] ========================
    if (tid < 512) {
        float hacc = bo1j;
#pragma unroll
        for (int q = 0; q < 32; q++) {
            const float4 hq = *(const float4*)&h2t[bb][q * 4];
            const float4 wq = *(const float4*)&wo1s[hid * 132 + q * 4];
            hacc = __fmaf_rn(hq.x, wq.x, hacc);
            hacc = __fmaf_rn(hq.y, wq.y, hacc);
            hacc = __fmaf_rn(hq.z, wq.z, hacc);
            hacc = __fmaf_rn(hq.w, wq.w, hacc);
        }
        float p = fmaxf(hacc, 0.f) * wo2v;
        p += __shfl_down(p, 32); p += __shfl_down(p, 16); p += __shfl_down(p, 8);
        p += __shfl_down(p, 4);  p += __shfl_down(p, 2);  p += __shfl_down(p, 1);
        if ((tid & 63) == 0) rp[tid >> 6] = p;
    }
    __syncthreads();
    if (tid < 4)
        out[(B0 + tid) * TGT_ + (TGT_ - 1)] = rp[2 * tid] + rp[2 * tid + 1] + bo2v;
}

// ---------------------------------------------------------------- launch ----
extern "C" void kernel_launch(void* const* d_in, const int* in_sizes, int n_in,
                              void* d_out, int out_size, void* d_ws, size_t ws_size,
                              hipStream_t stream) {
    const float* feat  = (const float*)d_in[0];
    const float* eWih0 = (const float*)d_in[1];
    const float* eWhh0 = (const float*)d_in[2];
    const float* eB0   = (const float*)d_in[3];
    const float* eWih1 = (const float*)d_in[4];
    const float* eWhh1 = (const float*)d_in[5];
    const float* eB1   = (const float*)d_in[6];
    const float* dWih0 = (const float*)d_in[7];
    const float* dWhh0 = (const float*)d_in[8];
    const float* dB0   = (const float*)d_in[9];
    const float* dWih1 = (const float*)d_in[10];
    const float* dWhh1 = (const float*)d_in[11];
    const float* dB1   = (const float*)d_in[12];
    const float* Wo1   = (const float*)d_in[13];
    const float* bo1   = (const float*)d_in[14];
    const float* Wo2   = (const float*)d_in[15];
    const float* bo2   = (const float*)d_in[16];

    const size_t SZ_BH = (size_t)B_ * H_;     // 131072
    const size_t SZ_W  = (size_t)G_ * H_;     // 65536
    const size_t fixed_f = 4 * SZ_BH + 4 * SZ_W + 2 * SZ_W + 64;

    // CL <= 42 so X1 + ys0T stay L3-resident
    static const int cands[] = {42, 32, 28, 24, 21, 16, 14, 12, 8, 7, 6, 4, 3, 2, 1};
    int CL = 1;
    for (int ci = 0; ci < 15; ci++) {
        const size_t need = (fixed_f + (size_t)cands[ci] * B_ * (H_ + G_)) * 4;
        if (need <= ws_size) { CL = cands[ci]; break; }
    }
    const int NC = T_ / CL;

    float* ws    = (float*)d_ws;
    float* ys0T  = ws;                                   // [CL][128][1024]
    float* X1    = ys0T + (size_t)CL * B_ * H_;          // [CL][1024][512]
    float* h1S   = X1 + (size_t)CL * B_ * G_;
    float* c1S   = h1S + SZ_BH;
    float* h2S   = c1S + SZ_BH;
    float* c2S   = h2S + SZ_BH;
    float* wtE0  = c2S + SZ_BH;
    float* wtE1x = wtE0 + SZ_W;
    float* wtE1h = wtE1x + SZ_W;
    float* wtD0  = wtE1h + SZ_W;
    float* wtD1p = wtD0 + SZ_W;            // [128][128][8] = 2*SZ_W

    PrepArgs pa;
    pa.t_src[0] = eWhh0; pa.t_dst[0] = wtE0;
    pa.t_src[1] = eWih1; pa.t_dst[1] = wtE1x;
    pa.t_src[2] = eWhh1; pa.t_dst[2] = wtE1h;
    pa.t_src[3] = dWhh0; pa.t_dst[3] = wtD0;
    pa.d1x = dWih1; pa.d1h = dWhh1; pa.pack = wtD1p;
    kPrep<<<5, 256, 0, stream>>>(pa);

    for (int c = 0; c < NC; c++) {
        const int t0 = c * CL;
        kA<<<NBLK_, 1024, 0, stream>>>(feat, wtE0, eWih0, eB0, ys0T, h1S, c1S, t0, CL);
        kX<<<dim3(8, 4, CL), 256, 0, stream>>>(ys0T, wtE1x, eB1, X1);
        kB2<<<NBLK_, 1024, 0, stream>>>(X1, wtE1h, h2S, c2S, t0, CL);
    }
    kD<<<NBLK_, 1024, 0, stream>>>(h1S, c1S, h2S, c2S,
                                   wtD0, dWih0, dB0,
                                   wtD1p, dB1,
                                   Wo1, bo1, Wo2, bo2,
                                   (float*)d_out);
}

// Round 10
// 4953.529 us; speedup vs baseline: 1.5293x; 1.5293x over previous
//
#include <hip/hip_runtime.h>

// Seq2SeqLSTMForecaster on MI355X — round 10.
// R9 lesson (counters): 1024-thr blocks get ~64 VGPR/thread from the compiler
// -> massive scratch spills (kD FETCH 4.4MB -> 5.8GB, WRITE 384KB -> 336MB).
// 512-thr __launch_bounds__(512,2) kernels allocate 112-128 VGPR, no spills.
// This round: exact R7 structure (best verified: 5.08ms) with ONE change:
//  - kX : 128x128 tile, 8x8 micro-tile (64 FMA per 4 LDS b128 reads, 2x the
//         arithmetic density of R7's 128x64/8x4), B read as two stride-4
//         float4s (2-way = free). Correctness-proven in R9.
//  - kA/kB2/kD : byte-identical to round 7 (512 thr, quad-gate, 4-way k).

#define B_    1024
#define T_    672
#define H_    128
#define G_    512      // 4*H
#define TGT_  96
#define NBLK_ 256

__device__ __forceinline__ float sigm(float x)   { return 1.f / (1.f + __expf(-x)); }
__device__ __forceinline__ float tanh_f(float x) { return 1.f - 2.f / (1.f + __expf(2.f * x)); }

// ---------------------------------------------------------------- prep ------
struct PrepArgs {
    const float* t_src[4];   // eWhh0, eWih1, eWhh1, dWhh0 -> [128,512]
    float*       t_dst[4];
    const float* d1x;  const float* d1h;  float* pack;   // dec L1 8-wide pack
};

__global__ void kPrep(PrepArgs a) {
    const int m = blockIdx.x;
    if (m < 4) {
        for (int i = threadIdx.x; i < G_ * H_; i += blockDim.x) {
            const int j = i >> 7, k = i & 127;
            a.t_dst[m][k * G_ + j] = a.t_src[m][i];
        }
    } else {
        // pack[(k*128 + j4)*8 + g]   = dWih1[j4+128g][k]  (g=0..3)
        // pack[(k*128 + j4)*8 + 4+g] = dWhh1[j4+128g][k]
        for (int i = threadIdx.x; i < H_ * H_; i += blockDim.x) {
            const int k = i >> 7, j4 = i & 127;
            float* p = a.pack + ((size_t)k * H_ + j4) * 8;
#pragma unroll
            for (int g = 0; g < 4; g++) {
                p[g]     = a.d1x[(j4 + 128 * g) * H_ + k];
                p[4 + g] = a.d1h[(j4 + 128 * g) * H_ + k];
            }
        }
    }
}

// --------------------------------- enc L0 (quad-gate, 4-way k, 512 thr) -----
__global__ __launch_bounds__(512, 2) void kA(
    const float* __restrict__ feat,   // [B,T]
    const float* __restrict__ whhT,   // [128,512] enc_Whh0^T
    const float* __restrict__ wih0,   // [512]
    const float* __restrict__ bias,   // [512]
    float* __restrict__ ys0T,         // [CL][128][1024] k-major
    float* __restrict__ hS, float* __restrict__ cS,
    int t0, int CL)
{
    __shared__ __align__(16) float h_sh[H_ * 4];     // [hid][bb]
    __shared__ __align__(16) float zp[4 * 2048];     // [kq][batch][gate]
    __shared__ __align__(16) float f_sh[84 * 4];

    const int tid = threadIdx.x;
    const int hid = tid & 127;        // = j4 (gate group) = act hid
    const int bb  = tid >> 7;         // = kq (k-quarter)  = act batch
    const int B0  = blockIdx.x * 4;

    float w[4][32];
#pragma unroll
    for (int g = 0; g < 4; g++)
#pragma unroll
        for (int k = 0; k < 32; k++)
            w[g][k] = whhT[(bb * 32 + k) * G_ + hid + 128 * g];

    const float bi = bias[hid],           bf = bias[hid + 128];
    const float bg = bias[hid + 256],     bo = bias[hid + 384];
    const float wxi = wih0[hid],          wxf = wih0[hid + 128];
    const float wxg = wih0[hid + 256],    wxo = wih0[hid + 384];

    for (int i = tid; i < CL * 4; i += 512)
        f_sh[i] = feat[(B0 + (i & 3)) * T_ + t0 + (i >> 2)];

    float c = 0.f;
    {
        float hv = 0.f;
        if (t0 != 0) { c = cS[(B0 + bb) * H_ + hid]; hv = hS[(B0 + bb) * H_ + hid]; }
        h_sh[hid * 4 + bb] = hv;
    }
    __syncthreads();

    const float* hb = h_sh + bb * 128;   // k-range bb*32..+31, [k][batch]
    for (int dt = 0; dt < CL; dt++) {
        if (dt > 0)
            ys0T[((size_t)(dt - 1) * H_ + (tid >> 2)) * B_ + B0 + (tid & 3)] = h_sh[tid];

        float a[4][4] = {};
#pragma unroll
        for (int k = 0; k < 32; k++) {
            const float4 h4 = *(const float4*)&hb[k * 4];   // uniform broadcast
#pragma unroll
            for (int g = 0; g < 4; g++) {
                a[g][0] = __fmaf_rn(h4.x, w[g][k], a[g][0]);
                a[g][1] = __fmaf_rn(h4.y, w[g][k], a[g][1]);
                a[g][2] = __fmaf_rn(h4.z, w[g][k], a[g][2]);
                a[g][3] = __fmaf_rn(h4.w, w[g][k], a[g][3]);
            }
        }
#pragma unroll
        for (int g = 0; g < 4; g++)
#pragma unroll
            for (int b = 0; b < 4; b++)
                zp[bb * 2048 + b * 512 + hid + 128 * g] = a[g][b];
        __syncthreads();

        {
            const float x = f_sh[dt * 4 + bb];
            const int base = bb * 512 + hid;
            float zi = __fmaf_rn(wxi, x, bi);
            float zf = __fmaf_rn(wxf, x, bf);
            float zg = __fmaf_rn(wxg, x, bg);
            float zo = __fmaf_rn(wxo, x, bo);
#pragma unroll
            for (int q = 0; q < 4; q++) {
                zi += zp[q * 2048 + base];
                zf += zp[q * 2048 + base + 128];
                zg += zp[q * 2048 + base + 256];
                zo += zp[q * 2048 + base + 384];
            }
            c = sigm(zf) * c + sigm(zi) * tanh_f(zg);
            h_sh[hid * 4 + bb] = sigm(zo) * tanh_f(c);
        }
        __syncthreads();
    }
    ys0T[((size_t)(CL - 1) * H_ + (tid >> 2)) * B_ + B0 + (tid & 3)] = h_sh[tid];
    hS[(B0 + bb) * H_ + hid] = h_sh[hid * 4 + bb];
    cS[(B0 + bb) * H_ + hid] = c;
}

// ----------------------- X1 GEMM: 128x128 tile, 8x8 micro, split-B ----------
__global__ __launch_bounds__(256, 2) void kX(
    const float* __restrict__ ys0T,   // [CL][128][1024]
    const float* __restrict__ wT,     // [128][512]
    const float* __restrict__ bias,   // [512]
    float* __restrict__ X1)           // [CL][1024][512]
{
    __shared__ __align__(16) float As[64][132];   // [k][m] 33.8KB
    __shared__ __align__(16) float Bs[64][132];   // [k][n] 33.8KB

    const int tid = threadIdx.x;
    const int m0 = blockIdx.x * 128;
    const int n0 = blockIdx.y * 128;
    const int dt = blockIdx.z;
    const float* A = ys0T + (size_t)dt * H_ * B_;

    const int tx = tid & 15, ty = tid >> 4;
    float acc[8][8] = {};

#pragma unroll
    for (int ks = 0; ks < 2; ks++) {
        if (ks) __syncthreads();
        for (int t = tid; t < 64 * 32; t += 256) {
            const int r = t >> 5, q = t & 31;
            *(float4*)&As[r][q * 4] = *(const float4*)&A[(size_t)(ks * 64 + r) * B_ + m0 + q * 4];
        }
        for (int t = tid; t < 64 * 32; t += 256) {
            const int r = t >> 5, q = t & 31;
            *(float4*)&Bs[r][q * 4] = *(const float4*)&wT[(size_t)(ks * 64 + r) * G_ + n0 + q * 4];
        }
        __syncthreads();

#pragma unroll 4
        for (int k = 0; k < 64; k++) {
            float av[8], bv[8];
            *(float4*)&av[0] = *(const float4*)&As[k][ty * 8];       // broadcast
            *(float4*)&av[4] = *(const float4*)&As[k][ty * 8 + 4];
            *(float4*)&bv[0] = *(const float4*)&Bs[k][tx * 4];       // stride-4: 2-way free
            *(float4*)&bv[4] = *(const float4*)&Bs[k][64 + tx * 4];
#pragma unroll
            for (int i = 0; i < 8; i++)
#pragma unroll
                for (int j = 0; j < 8; j++)
                    acc[i][j] = __fmaf_rn(av[i], bv[j], acc[i][j]);
        }
    }

    float4 bv0 = *(const float4*)&bias[n0 + tx * 4];
    float4 bv1 = *(const float4*)&bias[n0 + 64 + tx * 4];
#pragma unroll
    for (int i = 0; i < 8; i++) {
        float4 o0, o1;
        o0.x = acc[i][0] + bv0.x; o0.y = acc[i][1] + bv0.y;
        o0.z = acc[i][2] + bv0.z; o0.w = acc[i][3] + bv0.w;
        o1.x = acc[i][4] + bv1.x; o1.y = acc[i][5] + bv1.y;
        o1.z = acc[i][6] + bv1.z; o1.w = acc[i][7] + bv1.w;
        float* orow = &X1[((size_t)dt * B_ + m0 + ty * 8 + i) * G_ + n0];
        *(float4*)&orow[tx * 4]      = o0;
        *(float4*)&orow[64 + tx * 4] = o1;
    }
}

// --------------------------------- enc L1 (quad-gate, 4-way k, 512 thr) -----
__global__ __launch_bounds__(512, 2) void kB2(
    const float* __restrict__ X1,     // [CL][B][512] x-projection (+bias)
    const float* __restrict__ whhT,   // [128,512] enc_Whh1^T
    float* __restrict__ hS, float* __restrict__ cS,
    int t0, int CL)
{
    __shared__ __align__(16) float h_sh[H_ * 4];
    __shared__ __align__(16) float zp[4 * 2048];

    const int tid = threadIdx.x;
    const int hid = tid & 127;
    const int bb  = tid >> 7;
    const int B0  = blockIdx.x * 4;

    float w[4][32];
#pragma unroll
    for (int g = 0; g < 4; g++)
#pragma unroll
        for (int k = 0; k < 32; k++)
            w[g][k] = whhT[(bb * 32 + k) * G_ + hid + 128 * g];

    float c = 0.f;
    {
        float hv = 0.f;
        if (t0 != 0) { c = cS[(B0 + bb) * H_ + hid]; hv = hS[(B0 + bb) * H_ + hid]; }
        h_sh[hid * 4 + bb] = hv;
    }
    __syncthreads();

    const float* hb = h_sh + bb * 128;
    for (int dt = 0; dt < CL; dt++) {
        const size_t xb = ((size_t)dt * B_ + B0 + bb) * G_ + hid;
        const float xg0 = X1[xb];
        const float xg1 = X1[xb + 128];
        const float xg2 = X1[xb + 256];
        const float xg3 = X1[xb + 384];

        float a[4][4] = {};
#pragma unroll
        for (int k = 0; k < 32; k++) {
            const float4 h4 = *(const float4*)&hb[k * 4];
#pragma unroll
            for (int g = 0; g < 4; g++) {
                a[g][0] = __fmaf_rn(h4.x, w[g][k], a[g][0]);
                a[g][1] = __fmaf_rn(h4.y, w[g][k], a[g][1]);
                a[g][2] = __fmaf_rn(h4.z, w[g][k], a[g][2]);
                a[g][3] = __fmaf_rn(h4.w, w[g][k], a[g][3]);
            }
        }
#pragma unroll
        for (int g = 0; g < 4; g++)
#pragma unroll
            for (int b = 0; b < 4; b++)
                zp[bb * 2048 + b * 512 + hid + 128 * g] = a[g][b];
        __syncthreads();

        {
            const int base = bb * 512 + hid;
            float zi = xg0, zf = xg1, zg = xg2, zo = xg3;
#pragma unroll
            for (int q = 0; q < 4; q++) {
                zi += zp[q * 2048 + base];
                zf += zp[q * 2048 + base + 128];
                zg += zp[q * 2048 + base + 256];
                zo += zp[q * 2048 + base + 384];
            }
            c = sigm(zf) * c + sigm(zi) * tanh_f(zg);
            h_sh[hid * 4 + bb] = sigm(zo) * tanh_f(c);
        }
        __syncthreads();
    }
    hS[(B0 + bb) * H_ + hid] = h_sh[hid * 4 + bb];
    cS[(B0 + bb) * H_ + hid] = c;
}

// ------------------------------------------- decoder (quad-gate both dots) --
__global__ __launch_bounds__(512, 2) void kD(
    const float* __restrict__ h1S, const float* __restrict__ c1S,
    const float* __restrict__ h2S, const float* __restrict__ c2S,
    const float* __restrict__ whh0T,  // [128][512] dec_Whh0^T (register-resident)
    const float* __restrict__ wih0,   // [512]
    const float* __restrict__ b0,
    const float* __restrict__ packD1, // [128][128][8]
    const float* __restrict__ b1,
    const float* __restrict__ wo1,    // [128][128] W_out1 [hid][k] -> LDS rows
    const float* __restrict__ bo1,
    const float* __restrict__ wo2,
    const float* __restrict__ bo2,
    float* __restrict__ out)          // [B,TGT]
{
    __shared__ __align__(16) float h1_sh[H_ * 4];
    __shared__ __align__(16) float h2_sh[H_ * 4];
    __shared__ __align__(16) float h2t[4][H_];       // [bb][hid]
    __shared__ __align__(16) float zp[4 * 2048];
    __shared__ __align__(16) float wo1s[H_ * 132];   // rows [hid][k], pad 132
    __shared__ float rp[8];

    const int tid = threadIdx.x;
    const int hid = tid & 127;        // gate group / act hid
    const int bb  = tid >> 7;         // k-quarter / act batch
    const int B0  = blockIdx.x * 4;

    float w0[4][32];
#pragma unroll
    for (int g = 0; g < 4; g++)
#pragma unroll
        for (int k = 0; k < 32; k++)
            w0[g][k] = whh0T[(bb * 32 + k) * G_ + hid + 128 * g];

    const float b0i = b0[hid],        b0f = b0[hid + 128];
    const float b0g = b0[hid + 256],  b0o = b0[hid + 384];
    const float wxi = wih0[hid],      wxf = wih0[hid + 128];
    const float wxg = wih0[hid + 256], wxo = wih0[hid + 384];
    const float b1i = b1[hid],        b1f = b1[hid + 128];
    const float b1g = b1[hid + 256],  b1o = b1[hid + 384];

    for (int t = tid; t < H_ * 32; t += 512) {
        const int r = t >> 5, q = t & 31;
        *(float4*)&wo1s[r * 132 + q * 4] = *(const float4*)&wo1[r * H_ + q * 4];
    }

    const float wo2v = wo2[hid];
    const float bo1j = bo1[hid];
    const float bo2v = bo2[0];

    float c1 = c1S[(B0 + bb) * H_ + hid];
    float c2 = c2S[(B0 + bb) * H_ + hid];
    h1_sh[hid * 4 + bb] = h1S[(B0 + bb) * H_ + hid];
    {
        const float h2v = h2S[(B0 + bb) * H_ + hid];
        h2_sh[hid * 4 + bb] = h2v;
        h2t[bb][hid] = h2v;
    }
    if (tid < 8) rp[tid] = -0.5f * bo2v;   // so pred(step 0) = 0
    __syncthreads();

    const float* hb1 = h1_sh + bb * 128;
    const float* hb2 = h2_sh + bb * 128;
    const float* pk  = packD1 + ((size_t)bb * 32 * H_ + hid) * 8;

    for (int s = 0; s < TGT_; s++) {
        // ===== phase 1: L0 h-dot (reg weights) + head of h2(s-1), overlapped =====
        {
            float a[4][4] = {};
#pragma unroll
            for (int k = 0; k < 32; k++) {
                const float4 h4 = *(const float4*)&hb1[k * 4];
#pragma unroll
                for (int g = 0; g < 4; g++) {
                    a[g][0] = __fmaf_rn(h4.x, w0[g][k], a[g][0]);
                    a[g][1] = __fmaf_rn(h4.y, w0[g][k], a[g][1]);
                    a[g][2] = __fmaf_rn(h4.z, w0[g][k], a[g][2]);
                    a[g][3] = __fmaf_rn(h4.w, w0[g][k], a[g][3]);
                }
            }
#pragma unroll
            for (int g = 0; g < 4; g++)
#pragma unroll
                for (int b = 0; b < 4; b++)
                    zp[bb * 2048 + b * 512 + hid + 128 * g] = a[g][b];
        }
        {
            float hacc = bo1j;
#pragma unroll
            for (int q = 0; q < 32; q++) {
                const float4 hq = *(const float4*)&h2t[bb][q * 4];          // uniform
                const float4 wq = *(const float4*)&wo1s[hid * 132 + q * 4]; // lane-spread
                hacc = __fmaf_rn(hq.x, wq.x, hacc);
                hacc = __fmaf_rn(hq.y, wq.y, hacc);
                hacc = __fmaf_rn(hq.z, wq.z, hacc);
                hacc = __fmaf_rn(hq.w, wq.w, hacc);
            }
            float p = fmaxf(hacc, 0.f) * wo2v;
            p += __shfl_down(p, 32); p += __shfl_down(p, 16); p += __shfl_down(p, 8);
            p += __shfl_down(p, 4);  p += __shfl_down(p, 2);  p += __shfl_down(p, 1);
            if ((tid & 63) == 0) rp[tid >> 6] = p;
        }
        __syncthreads();

        // ===== phase 2: L0 act (+ x-term via pred), out write =====
        {
            const float pred = rp[2 * bb] + rp[2 * bb + 1] + bo2v;
            if (hid == 0 && s > 0) out[(B0 + bb) * TGT_ + (s - 1)] = pred;
            const int base = bb * 512 + hid;
            float zi = __fmaf_rn(wxi, pred, b0i);
            float zf = __fmaf_rn(wxf, pred, b0f);
            float zg = __fmaf_rn(wxg, pred, b0g);
            float zo = __fmaf_rn(wxo, pred, b0o);
#pragma unroll
            for (int q = 0; q < 4; q++) {
                zi += zp[q * 2048 + base];
                zf += zp[q * 2048 + base + 128];
                zg += zp[q * 2048 + base + 256];
                zo += zp[q * 2048 + base + 384];
            }
            c1 = sigm(zf) * c1 + sigm(zi) * tanh_f(zg);
            h1_sh[hid * 4 + bb] = sigm(zo) * tanh_f(c1);
        }
        __syncthreads();

        // ===== phase 3: L1 dot (L2 stream: 32 contiguous B per thread per k) =====
        {
            float d[4][4] = {};
#pragma unroll 8
            for (int k = 0; k < 32; k++) {
                const float4 wi = *(const float4*)&pk[(size_t)k * 1024];
                const float4 wh = *(const float4*)&pk[(size_t)k * 1024 + 4];
                const float4 p1 = *(const float4*)&hb1[k * 4];
                const float4 p2 = *(const float4*)&hb2[k * 4];
                d[0][0] = __fmaf_rn(p1.x, wi.x, __fmaf_rn(p2.x, wh.x, d[0][0]));
                d[0][1] = __fmaf_rn(p1.y, wi.x, __fmaf_rn(p2.y, wh.x, d[0][1]));
                d[0][2] = __fmaf_rn(p1.z, wi.x, __fmaf_rn(p2.z, wh.x, d[0][2]));
                d[0][3] = __fmaf_rn(p1.w, wi.x, __fmaf_rn(p2.w, wh.x, d[0][3]));
                d[1][0] = __fmaf_rn(p1.x, wi.y, __fmaf_rn(p2.x, wh.y, d[1][0]));
                d[1][1] = __fmaf_rn(p1.y, wi.y, __fmaf_rn(p2.y, wh.y, d[1][1]));
                d[1][2] = __fmaf_rn(p1.z, wi.y, __fmaf_rn(p2.z, wh.y, d[1][2]));
                d[1][3] = __fmaf_rn(p1.w, wi.y, __fmaf_rn(p2.w, wh.y, d[1][3]));
                d[2][0] = __fmaf_rn(p1.x, wi.z, __fmaf_rn(p2.x, wh.z, d[2][0]));
                d[2][1] = __fmaf_rn(p1.y, wi.z, __fmaf_rn(p2.y, wh.z, d[2][1]));
                d[2][2] = __fmaf_rn(p1.z, wi.z, __fmaf_rn(p2.z, wh.z, d[2][2]));
                d[2][3] = __fmaf_rn(p1.w, wi.z, __fmaf_rn(p2.w, wh.z, d[2][3]));
                d[3][0] = __fmaf_rn(p1.x, wi.w, __fmaf_rn(p2.x, wh.w, d[3][0]));
                d[3][1] = __fmaf_rn(p1.y, wi.w, __fmaf_rn(p2.y, wh.w, d[3][1]));
                d[3][2] = __fmaf_rn(p1.z, wi.w, __fmaf_rn(p2.z, wh.w, d[3][2]));
                d[3][3] = __fmaf_rn(p1.w, wi.w, __fmaf_rn(p2.w, wh.w, d[3][3]));
            }
#pragma unroll
            for (int g = 0; g < 4; g++)
#pragma unroll
                for (int b = 0; b < 4; b++)
                    zp[bb * 2048 + b * 512 + hid + 128 * g] = d[g][b];
        }
        __syncthreads();

        // ===== phase 4: L1 act =====
        {
            const int base = bb * 512 + hid;
            float zi = b1i, zf = b1f, zg = b1g, zo = b1o;
#pragma unroll
            for (int q = 0; q < 4; q++) {
                zi += zp[q * 2048 + base];
                zf += zp[q * 2048 + base + 128];
                zg += zp[q * 2048 + base + 256];
                zo += zp[q * 2048 + base + 384];
            }
            c2 = sigm(zf) * c2 + sigm(zi) * tanh_f(zg);
            const float h2v = sigm(zo) * tanh_f(c2);
            h2_sh[hid * 4 + bb] = h2v;
            h2t[bb][hid] = h2v;
        }
        __syncthreads();
    }

    // ===== epilogue: head of final h2 -> out[..][95] =====
    {
        float hacc = bo1j;
#pragma unroll
        for (int q = 0; q < 32; q++) {
            const float4 hq = *(const float4*)&h2t[bb][q * 4];
            const float4 wq = *(const float4*)&wo1s[hid * 132 + q * 4];
            hacc = __fmaf_rn(hq.x, wq.x, hacc);
            hacc = __fmaf_rn(hq.y, wq.y, hacc);
            hacc = __fmaf_rn(hq.z, wq.z, hacc);
            hacc = __fmaf_rn(hq.w, wq.w, hacc);
        }
        float p = fmaxf(hacc, 0.f) * wo2v;
        p += __shfl_down(p, 32); p += __shfl_down(p, 16); p += __shfl_down(p, 8);
        p += __shfl_down(p, 4);  p += __shfl_down(p, 2);  p += __shfl_down(p, 1);
        if ((tid & 63) == 0) rp[tid >> 6] = p;
    }
    __syncthreads();
    if (tid < 4)
        out[(B0 + tid) * TGT_ + (TGT_ - 1)] = rp[2 * tid] + rp[2 * tid + 1] + bo2v;
}

// ---------------------------------------------------------------- launch ----
extern "C" void kernel_launch(void* const* d_in, const int* in_sizes, int n_in,
                              void* d_out, int out_size, void* d_ws, size_t ws_size,
                              hipStream_t stream) {
    const float* feat  = (const float*)d_in[0];
    const float* eWih0 = (const float*)d_in[1];
    const float* eWhh0 = (const float*)d_in[2];
    const float* eB0   = (const float*)d_in[3];
    const float* eWih1 = (const float*)d_in[4];
    const float* eWhh1 = (const float*)d_in[5];
    const float* eB1   = (const float*)d_in[6];
    const float* dWih0 = (const float*)d_in[7];
    const float* dWhh0 = (const float*)d_in[8];
    const float* dB0   = (const float*)d_in[9];
    const float* dWih1 = (const float*)d_in[10];
    const float* dWhh1 = (const float*)d_in[11];
    const float* dB1   = (const float*)d_in[12];
    const float* Wo1   = (const float*)d_in[13];
    const float* bo1   = (const float*)d_in[14];
    const float* Wo2   = (const float*)d_in[15];
    const float* bo2   = (const float*)d_in[16];

    const size_t SZ_BH = (size_t)B_ * H_;     // 131072
    const size_t SZ_W  = (size_t)G_ * H_;     // 65536
    const size_t fixed_f = 4 * SZ_BH + 4 * SZ_W + 2 * SZ_W + 64;

    // CL <= 42 so X1 + ys0T stay L3-resident
    static const int cands[] = {42, 32, 28, 24, 21, 16, 14, 12, 8, 7, 6, 4, 3, 2, 1};
    int CL = 1;
    for (int ci = 0; ci < 15; ci++) {
        const size_t need = (fixed_f + (size_t)cands[ci] * B_ * (H_ + G_)) * 4;
        if (need <= ws_size) { CL = cands[ci]; break; }
    }
    const int NC = T_ / CL;

    float* ws    = (float*)d_ws;
    float* ys0T  = ws;                                   // [CL][128][1024]
    float* X1    = ys0T + (size_t)CL * B_ * H_;          // [CL][1024][512]
    float* h1S   = X1 + (size_t)CL * B_ * G_;
    float* c1S   = h1S + SZ_BH;
    float* h2S   = c1S + SZ_BH;
    float* c2S   = h2S + SZ_BH;
    float* wtE0  = c2S + SZ_BH;
    float* wtE1x = wtE0 + SZ_W;
    float* wtE1h = wtE1x + SZ_W;
    float* wtD0  = wtE1h + SZ_W;
    float* wtD1p = wtD0 + SZ_W;            // [128][128][8] = 2*SZ_W

    PrepArgs pa;
    pa.t_src[0] = eWhh0; pa.t_dst[0] = wtE0;
    pa.t_src[1] = eWih1; pa.t_dst[1] = wtE1x;
    pa.t_src[2] = eWhh1; pa.t_dst[2] = wtE1h;
    pa.t_src[3] = dWhh0; pa.t_dst[3] = wtD0;
    pa.d1x = dWih1; pa.d1h = dWhh1; pa.pack = wtD1p;
    kPrep<<<5, 256, 0, stream>>>(pa);

    for (int c = 0; c < NC; c++) {
        const int t0 = c * CL;
        kA<<<NBLK_, 512, 0, stream>>>(feat, wtE0, eWih0, eB0, ys0T, h1S, c1S, t0, CL);
        kX<<<dim3(8, 4, CL), 256, 0, stream>>>(ys0T, wtE1x, eB1, X1);
        kB2<<<NBLK_, 512, 0, stream>>>(X1, wtE1h, h2S, c2S, t0, CL);
    }
    kD<<<NBLK_, 512, 0, stream>>>(h1S, c1S, h2S, c2S,
                                  wtD0, dWih0, dB0,
                                  wtD1p, dB1,
                                  Wo1, bo1, Wo2, bo2,
                                  (float*)d_out);
}